// Round 4
// baseline (607.265 us; speedup 1.0000x reference)
//
#include <hip/hip_runtime.h>

#define IN 906
#define TT 512
#define NB 128

// ---------------------------------------------------------------------------
__device__ __forceinline__ float fsigm(float x) {
    float e = __builtin_amdgcn_exp2f(-1.4426950408889634f * x);   // exp(-x)
    return __builtin_amdgcn_rcpf(1.f + e);
}
__device__ __forceinline__ float ftanh(float x) {
    float e = __builtin_amdgcn_exp2f(-2.8853900817779268f * x);   // exp(-2x)
    return 2.f * __builtin_amdgcn_rcpf(1.f + e) - 1.f;
}
template <int M>
__device__ __forceinline__ float quad_bcast(float v) {
    constexpr int ctrl = M | (M << 2) | (M << 4) | (M << 6);
    return __int_as_float(
        __builtin_amdgcn_mov_dpp(__float_as_int(v), ctrl, 0xf, 0xf, true));
}

// ---------------------------------------------------------------------------
// GEMM v5: xp = x @ W^T + b1 + b2, stored permuted xp[row][(j&3)*4 + (j>>2)].
//
// v4 counters (149us): VALUBusy 24.6%, HBM 10.6%, conflicts 0 => pure
// latency-stall on the 8-slice serial K-chain (1-deep prefetch gives ~770
// issueable cyc between load and use vs ~900cyc HBM latency, re-exposed
// every slice). v5 splits K across the block's waves instead:
//   block = 8 rows = 2 row-groups x 2 k-halves (4 waves);
//   each wave: 4 serial slices over its 512-col half (k = kh*512+s*128+2l),
//   v4's proven acc[64] + 6-step fold-reduce, then a 512B LDS 2-way
//   k-reduction merges the halves. Per-block lifetime ~1900cyc, 3 blocks/CU
//   resident, 32 generations/CU => latency exposed ~once per block.
//   x loads issued before W (HBM vs L2). All loads 512B/wave-instr.
// W re-read: 8192 blocks x 58KB = 475MB from L2 (~10TB/s at target) - safe.
// Floors: x ~25-37us (HBM/L3), FMA 12us, W-L2 14us. Target gemm 50-65us.
__global__ __launch_bounds__(256, 3)
void gemm_xp(const float* __restrict__ x, const float* __restrict__ W,
             const float* __restrict__ b1, const float* __restrict__ b2,
             float* __restrict__ xp)
{
    __shared__ float red[2][64];
    const int tid = threadIdx.x;
    const int l   = tid & 63;
    const int w   = tid >> 6;            // 0..3
    const int kh  = w & 1;               // k-half: cols kh*512 .. kh*512+511
    const int rg  = w >> 1;              // row-group
    const size_t row0 = (size_t)blockIdx.x * 8 + (size_t)rg * 4;

    float acc[64];                       // acc[r*16 + j]
#pragma unroll
    for (int i = 0; i < 64; ++i) acc[i] = 0.f;

    const int kl = kh * 512 + l * 2;     // lane's base col within k-half

    float2 wA[16], wB[16];
    float2 xA[4],  xB[4];

    auto load_slice = [&](int s, float2 (&wv)[16], float2 (&xv)[4]) {
        const int k = kl + s * 128;
        if (kh == 0 || s < 3) {                   // k <= 894+... in range
#pragma unroll
            for (int r = 0; r < 4; ++r)           // x first: HBM latency
                xv[r] = *(const float2*)(x + (row0 + r) * IN + k);
#pragma unroll
            for (int jj = 0; jj < 16; ++jj)       // W second: L2 latency
                wv[jj] = *(const float2*)(W + jj * IN + k);
        } else {                                  // tail: k = 896+2l
            const bool ok = (k < IN);             // pair-granular (906 even)
            const int  kc = ok ? k : 0;           // clamped, in-bounds
#pragma unroll
            for (int r = 0; r < 4; ++r)
                xv[r] = *(const float2*)(x + (row0 + r) * IN + kc);
#pragma unroll
            for (int jj = 0; jj < 16; ++jj) {
                float2 t = *(const float2*)(W + jj * IN + kc);
                wv[jj].x = ok ? t.x : 0.f;        // zero W => product zero
                wv[jj].y = ok ? t.y : 0.f;
            }
        }
    };
    auto mac_slice = [&](float2 (&wv)[16], float2 (&xv)[4]) {
#pragma unroll
        for (int r = 0; r < 4; ++r)
#pragma unroll
            for (int jj = 0; jj < 16; ++jj) {
                acc[r * 16 + jj] = fmaf(xv[r].x, wv[jj].x, acc[r * 16 + jj]);
                acc[r * 16 + jj] = fmaf(xv[r].y, wv[jj].y, acc[r * 16 + jj]);
            }
    };

    load_slice(0, wA, xA);
#pragma unroll
    for (int s = 0; s < 4; ++s) {                 // static buffer picks
        if (s + 1 < 4) {
            if (s & 1) load_slice(s + 1, wA, xA);
            else       load_slice(s + 1, wB, xB);
        }
        if (s & 1) mac_slice(wB, xB);
        else       mac_slice(wA, xA);
    }

    // ---- fold-reduce: 64 partials x 64 lanes -> 1 total per lane ----------
    // j bits 0..3 -> lane bits 0..3 (xor 1,2,4,8); r bits -> lane bits 4,5
    // (xor 16,32). Final: lane l holds this k-half's total for
    // r=(l>>4)&3, j=l&15.   [identical to v4's verified fold]
    float u1[32];
#pragma unroll
    for (int i = 0; i < 32; ++i) {
        float lo = acc[2 * i], hi = acc[2 * i + 1];
        float mi = (l & 1) ? hi : lo;
        float ot = (l & 1) ? lo : hi;
        u1[i] = mi + __shfl_xor(ot, 1);
    }
    float u2[16];
#pragma unroll
    for (int i = 0; i < 16; ++i) {
        float lo = u1[2 * i], hi = u1[2 * i + 1];
        float mi = (l & 2) ? hi : lo;
        float ot = (l & 2) ? lo : hi;
        u2[i] = mi + __shfl_xor(ot, 2);
    }
    float u3[8];
#pragma unroll
    for (int i = 0; i < 8; ++i) {
        float lo = u2[2 * i], hi = u2[2 * i + 1];
        float mi = (l & 4) ? hi : lo;
        float ot = (l & 4) ? lo : hi;
        u3[i] = mi + __shfl_xor(ot, 4);
    }
    float u4[4];
#pragma unroll
    for (int i = 0; i < 4; ++i) {
        float lo = u3[2 * i], hi = u3[2 * i + 1];
        float mi = (l & 8) ? hi : lo;
        float ot = (l & 8) ? lo : hi;
        u4[i] = mi + __shfl_xor(ot, 8);
    }
    float u5[2];
#pragma unroll
    for (int i = 0; i < 2; ++i) {
        float lo = u4[2 * i], hi = u4[2 * i + 1];
        float mi = (l & 16) ? hi : lo;
        float ot = (l & 16) ? lo : hi;
        u5[i] = mi + __shfl_xor(ot, 16);
    }
    float tot;
    {
        float lo = u5[0], hi = u5[1];
        float mi = (l & 32) ? hi : lo;
        float ot = (l & 32) ? lo : hi;
        tot = mi + __shfl_xor(ot, 32);
    }

    // ---- 2-way k-half reduction via LDS, then writeout ---------------------
    if (kh == 1) red[rg][l] = tot;
    __syncthreads();
    if (kh == 0) {
        tot += red[rg][l];
        const int jo = l & 15;
        const int g  = (l >> 4) & 3;
        const int pj = (jo & 3) * 4 + (jo >> 2);  // permuted position
        xp[(row0 + (size_t)g) * 16 + pj] = tot + b1[jo] + b2[jo];
    }
}

// ---------------------------------------------------------------------------
// Recurrence kernel: 8 blocks x 256 threads, 16 batches per block.
// wave 0: 512-step forward recurrence (quad per batch, DPP h-broadcast),
//         16-step-deep xp prefetch (covers ~900cyc cross-XCD/HBM latency;
//         depth 4 left steps memory-throttled at ~225cyc vs ~70cyc chain).
// waves 1-3: backward-direction GEMV (f-gate irrelevant, c0=0) -> LDS.
// epilogue (wave 0): backward cell + output projection.
__global__ __launch_bounds__(256)
void frec(const float* __restrict__ xp, const float* __restrict__ x,
          const float* __restrict__ Whh, const float* __restrict__ Wb,
          const float* __restrict__ bb1, const float* __restrict__ bb2,
          const float* __restrict__ Wout, const float* __restrict__ bout,
          float* __restrict__ out)
{
    __shared__ float bg[16][12];
    const int tid = threadIdx.x;

    float h0 = 0.f, h1 = 0.f, h2 = 0.f, h3 = 0.f;

    if (tid >= 64) {
        // ---- backward GEMV: 192 lanes = 16 batches x 12 gate rows ----
        const int gl = tid - 64;          // 0..191
        const int r  = gl >> 4;           // 0..11
        const int bq = gl & 15;
        const int b  = blockIdx.x * 16 + bq;
        const int gr = (r < 4) ? r : r + 4;   // rows: i 0-3, g 8-11, o 12-15
        const float2* __restrict__ xr  = (const float2*)(x + ((size_t)b * TT + (TT - 1)) * IN);
        const float2* __restrict__ wrp = (const float2*)(Wb + gr * IN);
        float s0 = 0.f, s1 = 0.f;
        int j = 0;
        for (; j + 8 <= 453; j += 8) {
#pragma unroll
            for (int u = 0; u < 8; ++u) {
                float2 a = xr[j + u];
                float2 w = wrp[j + u];
                s0 = fmaf(a.x, w.x, s0);
                s1 = fmaf(a.y, w.y, s1);
            }
        }
        for (; j < 453; ++j) {
            float2 a = xr[j];
            float2 w = wrp[j];
            s0 = fmaf(a.x, w.x, s0);
            s1 = fmaf(a.y, w.y, s1);
        }
        bg[bq][r] = s0 + s1 + bb1[gr] + bb2[gr];
    } else {
        // ---- forward recurrence ----
        const int k = tid & 3;
        const int b = blockIdx.x * 16 + (tid >> 2);

        float Wi[4], Wf4[4], Wg[4], Wo[4];
#pragma unroll
        for (int m = 0; m < 4; ++m) {
            Wi[m]  = Whh[(k)      * 4 + m];
            Wf4[m] = Whh[(4 + k)  * 4 + m];
            Wg[m]  = Whh[(8 + k)  * 4 + m];
            Wo[m]  = Whh[(12 + k) * 4 + m];
        }

        const float4* __restrict__ xq = (const float4*)xp;
        const size_t base = (size_t)b * TT * 4 + k;

        float4 pf[16];
#pragma unroll
        for (int i = 0; i < 16; ++i) pf[i] = xq[base + (size_t)i * 4];

        float c = 0.f;
        for (int t = 0; t < TT; t += 16) {
#pragma unroll
            for (int u = 0; u < 16; ++u) {
                float4 cur = pf[u];
                int tn = t + 16 + u;
                int tc = (tn < TT) ? tn : (TT - 1);
                pf[u] = xq[base + (size_t)tc * 4];   // prefetch 16 ahead

                float gi = cur.x + h0 * Wi[0]  + h1 * Wi[1]  + h2 * Wi[2]  + h3 * Wi[3];
                float gf = cur.y + h0 * Wf4[0] + h1 * Wf4[1] + h2 * Wf4[2] + h3 * Wf4[3];
                float gg = cur.z + h0 * Wg[0]  + h1 * Wg[1]  + h2 * Wg[2]  + h3 * Wg[3];
                float go = cur.w + h0 * Wo[0]  + h1 * Wo[1]  + h2 * Wo[2]  + h3 * Wo[3];

                float si = fsigm(gi);
                float sf = fsigm(gf);
                float tg = ftanh(gg);
                float so = fsigm(go);

                c = sf * c + si * tg;
                float h = so * ftanh(c);

                h0 = quad_bcast<0>(h);
                h1 = quad_bcast<1>(h);
                h2 = quad_bcast<2>(h);
                h3 = quad_bcast<3>(h);
            }
        }
    }

    __syncthreads();

    if (tid < 64) {
        const int k  = tid & 3;
        const int bq = tid >> 2;
        const int b  = blockIdx.x * 16 + bq;

        float gib = bg[bq][k];
        float ggb = bg[bq][4 + k];
        float gob = bg[bq][8 + k];
        float hbk = fsigm(gob) * ftanh(fsigm(gib) * ftanh(ggb));
        float hb0 = quad_bcast<0>(hbk);
        float hb1 = quad_bcast<1>(hbk);
        float hb2 = quad_bcast<2>(hbk);
        float hb3 = quad_bcast<3>(hbk);

        float o0 = bout[0]
                 + h0  * Wout[0]  + h1  * Wout[1]  + h2  * Wout[2]  + h3  * Wout[3]
                 + hb0 * Wout[4]  + hb1 * Wout[5]  + hb2 * Wout[6]  + hb3 * Wout[7];
        float o1 = bout[1]
                 + h0  * Wout[8]  + h1  * Wout[9]  + h2  * Wout[10] + h3  * Wout[11]
                 + hb0 * Wout[12] + hb1 * Wout[13] + hb2 * Wout[14] + hb3 * Wout[15];

        if (k == 0) {
            out[b * 2 + 0] = o0;
            out[b * 2 + 1] = o1;
        }
    }
}

// ---------------------------------------------------------------------------
extern "C" void kernel_launch(void* const* d_in, const int* in_sizes, int n_in,
                              void* d_out, int out_size, void* d_ws, size_t ws_size,
                              hipStream_t stream)
{
    const float* x    = (const float*)d_in[0];
    const float* Wihf = (const float*)d_in[1];
    const float* Whhf = (const float*)d_in[2];
    const float* bihf = (const float*)d_in[3];
    const float* bhhf = (const float*)d_in[4];
    const float* Wihb = (const float*)d_in[5];
    const float* bihb = (const float*)d_in[7];
    const float* bhhb = (const float*)d_in[8];
    const float* Wout = (const float*)d_in[9];
    const float* bout = (const float*)d_in[10];

    float* xp = (float*)d_ws;   // 65536 rows x 16 floats = 4,194,304 B exactly

    // 65536 rows / (8 rows per block) = 8192 blocks
    gemm_xp<<<8192, 256, 0, stream>>>(x, Wihf, bihf, bhhf, xp);
    frec<<<8, 256, 0, stream>>>(xp, x, Whhf, Wihb, bihb, bhhb, Wout, bout,
                                (float*)d_out);
}

// Round 5
// 450.519 us; speedup vs baseline: 1.3479x; 1.3479x over previous
//
#include <hip/hip_runtime.h>

#define IN 906
#define TT 512
#define NB 128

// ---------------------------------------------------------------------------
__device__ __forceinline__ float fsigm(float x) {
    float e = __builtin_amdgcn_exp2f(-1.4426950408889634f * x);   // exp(-x)
    return __builtin_amdgcn_rcpf(1.f + e);
}
__device__ __forceinline__ float ftanh(float x) {
    float e = __builtin_amdgcn_exp2f(-2.8853900817779268f * x);   // exp(-2x)
    return 2.f * __builtin_amdgcn_rcpf(1.f + e) - 1.f;
}
template <int M>
__device__ __forceinline__ float quad_bcast(float v) {
    constexpr int ctrl = M | (M << 2) | (M << 4) | (M << 6);
    return __int_as_float(
        __builtin_amdgcn_mov_dpp(__float_as_int(v), ctrl, 0xf, 0xf, true));
}

// ---------------------------------------------------------------------------
// GEMM v6: xp = x @ W^T + b1 + b2, stored permuted xp[row][(j&3)*4 + (j>>2)].
//
// History: v3 (128-row blocks, 2-buf LDS, 1 barrier/chunk) ~98us; analysis
// shows ~70% of each 4050-cyc chunk slot is idle = barrier-serialized global
// latency (issue work only ~550cyc/wave; LDS reads broadcast-cheap). v4/v5
// (k-across-lanes, no LDS) died on latency-serial slices resp. scratch
// spills (v5 WRITE_SIZE 362MB).
//
// v6 keeps v3's proven dataflow, attacks only the idle fraction:
//   - 64-row blocks, grid 1024 = exactly 4 blocks/CU resident (was 2),
//     independent barriers overlap each other's drains; zero tail.
//   - triple-buffered LDS, 2-chunk-deep pipeline (T14 issue-early/
//     write-late): loads for chunk c+2 issued at top of iter c, written
//     to LDS after compute(c), consumed at iter c+2 => ~2 compute spans
//     x 4 blocks to cover ~900cyc latency; vmcnt off the critical path.
//   - registers tiny (~50 VGPR), plain launch_bounds: no spill, no AGPR
//     dependence (v5's failure mode).
// LDS 36KB/block (caps at 4/CU). Banks: x-read b64 conflict-free, w-read
// broadcast, stage-writes worst 4-way on 8 instrs (free-ish per m136).
__global__ __launch_bounds__(256)
void gemm_xp(const float* __restrict__ x, const float* __restrict__ W,
             const float* __restrict__ b1, const float* __restrict__ b2,
             float* __restrict__ xp)
{
    __shared__ float sx[3][32][68];    // [buf][col][row(64)+pad4]
    __shared__ float sw[3][32][16];    // [buf][col][out]
    __shared__ float red[8][128];      // k-half merge: [r*4+m][rem]
    const int tid = threadIdx.x;
    const size_t rowbase = (size_t)blockIdx.x * 64;

    // x staging map: 4 threads per row, 8 cols each (4 float2)
    const int srow = tid >> 2;          // 0..63
    const int sseg = tid & 3;           // cols sseg*8 .. sseg*8+7
    const float* __restrict__ xrow = x + (rowbase + srow) * IN + sseg * 8;
    // W staging map: 16 threads per out-row, 2 cols each
    const int wout = tid >> 4;          // 0..15
    const int wcc  = (tid & 15) * 2;    // 0,2,..,30

    // compute map: 2 k-halves x 32 rowgroups(2 rows) x 4 outgroups
    const int kh  = tid >> 7;           // 0..1 -> cols kh*16 + 0..15
    const int rem = tid & 127;
    const int rg  = rem >> 2;           // 0..31
    const int og  = rem & 3;            // 0..3
    const int r0  = rg * 2;             // rows r0, r0+1

    float2 xr[4];
    float2 wr;
    float acc[2][4];
#pragma unroll
    for (int r = 0; r < 2; ++r)
#pragma unroll
        for (int m = 0; m < 4; ++m) acc[r][m] = 0.f;

    auto load_chunk = [&](int c) {
        const int k0 = c * 32;
        if (c < 28) {
#pragma unroll
            for (int q = 0; q < 4; ++q)
                xr[q] = *(const float2*)(xrow + k0 + q * 2);
            wr = *(const float2*)(W + wout * IN + k0 + wcc);
        } else {                         // tail chunk: cols 896..905 valid
#pragma unroll
            for (int q = 0; q < 4; ++q) {
                int col = k0 + sseg * 8 + q * 2;
                bool ok = (col < IN);    // pair-granular (IN even)
                xr[q].x = ok ? xrow[k0 + q * 2]     : 0.f;
                xr[q].y = ok ? xrow[k0 + q * 2 + 1] : 0.f;
            }
            int colw = k0 + wcc;
            bool okw = (colw < IN);
            wr.x = okw ? W[wout * IN + colw]     : 0.f;
            wr.y = okw ? W[wout * IN + colw + 1] : 0.f;
        }
    };
    auto write_chunk = [&](int buf) {
#pragma unroll
        for (int q = 0; q < 4; ++q) {
            int cc = sseg * 8 + q * 2;
            sx[buf][cc][srow]     = xr[q].x;
            sx[buf][cc + 1][srow] = xr[q].y;
        }
        sw[buf][wcc][wout]     = wr.x;
        sw[buf][wcc + 1][wout] = wr.y;
    };
    auto compute = [&](int buf) {
#pragma unroll
        for (int cc2 = 0; cc2 < 16; ++cc2) {
            const int cc = kh * 16 + cc2;
            float2 xv = *(const float2*)&sx[buf][cc][r0];
            float4 wv = *(const float4*)&sw[buf][cc][og * 4];
            acc[0][0] = fmaf(xv.x, wv.x, acc[0][0]);
            acc[0][1] = fmaf(xv.x, wv.y, acc[0][1]);
            acc[0][2] = fmaf(xv.x, wv.z, acc[0][2]);
            acc[0][3] = fmaf(xv.x, wv.w, acc[0][3]);
            acc[1][0] = fmaf(xv.y, wv.x, acc[1][0]);
            acc[1][1] = fmaf(xv.y, wv.y, acc[1][1]);
            acc[1][2] = fmaf(xv.y, wv.z, acc[1][2]);
            acc[1][3] = fmaf(xv.y, wv.w, acc[1][3]);
        }
    };

    // prologue: chunks 0 and 1 staged (latency exposed once per block)
    load_chunk(0);  write_chunk(0);
    load_chunk(1);  write_chunk(1);
    __syncthreads();

    for (int c = 0; c < 29; ++c) {
        if (c + 2 < 29) load_chunk(c + 2);       // issue early (T14)
        compute(c % 3);                          // covers load latency
        if (c + 2 < 29) write_chunk((c + 2) % 3);// write late (post-vmcnt)
        __syncthreads();
    }

    // ---- k-half merge via LDS, then writeout -------------------------------
    if (kh == 1) {
#pragma unroll
        for (int r = 0; r < 2; ++r)
#pragma unroll
            for (int m = 0; m < 4; ++m)
                red[r * 4 + m][rem] = acc[r][m];
    }
    __syncthreads();
    if (kh == 0) {
#pragma unroll
        for (int r = 0; r < 2; ++r) {
            const size_t row = rowbase + r0 + r;
#pragma unroll
            for (int m = 0; m < 4; ++m) {
                const int j = og * 4 + m;
                float v = acc[r][m] + red[r * 4 + m][rem];
                // permuted pos = (j&3)*4 + (j>>2) = m*4 + og
                xp[row * 16 + m * 4 + og] = v + b1[j] + b2[j];
            }
        }
    }
}

// ---------------------------------------------------------------------------
// Recurrence kernel: 8 blocks x 256 threads, 16 batches per block.
// wave 0: 512-step forward recurrence (quad per batch, DPP h-broadcast),
//         16-step-deep xp prefetch (covers ~900cyc cross-XCD/HBM latency;
//         depth 4 left steps memory-throttled at ~225cyc vs ~70cyc chain).
// waves 1-3: backward-direction GEMV (f-gate irrelevant, c0=0) -> LDS.
// epilogue (wave 0): backward cell + output projection.
__global__ __launch_bounds__(256)
void frec(const float* __restrict__ xp, const float* __restrict__ x,
          const float* __restrict__ Whh, const float* __restrict__ Wb,
          const float* __restrict__ bb1, const float* __restrict__ bb2,
          const float* __restrict__ Wout, const float* __restrict__ bout,
          float* __restrict__ out)
{
    __shared__ float bg[16][12];
    const int tid = threadIdx.x;

    float h0 = 0.f, h1 = 0.f, h2 = 0.f, h3 = 0.f;

    if (tid >= 64) {
        // ---- backward GEMV: 192 lanes = 16 batches x 12 gate rows ----
        const int gl = tid - 64;          // 0..191
        const int r  = gl >> 4;           // 0..11
        const int bq = gl & 15;
        const int b  = blockIdx.x * 16 + bq;
        const int gr = (r < 4) ? r : r + 4;   // rows: i 0-3, g 8-11, o 12-15
        const float2* __restrict__ xr  = (const float2*)(x + ((size_t)b * TT + (TT - 1)) * IN);
        const float2* __restrict__ wrp = (const float2*)(Wb + gr * IN);
        float s0 = 0.f, s1 = 0.f;
        int j = 0;
        for (; j + 8 <= 453; j += 8) {
#pragma unroll
            for (int u = 0; u < 8; ++u) {
                float2 a = xr[j + u];
                float2 w = wrp[j + u];
                s0 = fmaf(a.x, w.x, s0);
                s1 = fmaf(a.y, w.y, s1);
            }
        }
        for (; j < 453; ++j) {
            float2 a = xr[j];
            float2 w = wrp[j];
            s0 = fmaf(a.x, w.x, s0);
            s1 = fmaf(a.y, w.y, s1);
        }
        bg[bq][r] = s0 + s1 + bb1[gr] + bb2[gr];
    } else {
        // ---- forward recurrence ----
        const int k = tid & 3;
        const int b = blockIdx.x * 16 + (tid >> 2);

        float Wi[4], Wf4[4], Wg[4], Wo[4];
#pragma unroll
        for (int m = 0; m < 4; ++m) {
            Wi[m]  = Whh[(k)      * 4 + m];
            Wf4[m] = Whh[(4 + k)  * 4 + m];
            Wg[m]  = Whh[(8 + k)  * 4 + m];
            Wo[m]  = Whh[(12 + k) * 4 + m];
        }

        const float4* __restrict__ xq = (const float4*)xp;
        const size_t base = (size_t)b * TT * 4 + k;

        float4 pf[16];
#pragma unroll
        for (int i = 0; i < 16; ++i) pf[i] = xq[base + (size_t)i * 4];

        float c = 0.f;
        for (int t = 0; t < TT; t += 16) {
#pragma unroll
            for (int u = 0; u < 16; ++u) {
                float4 cur = pf[u];
                int tn = t + 16 + u;
                int tc = (tn < TT) ? tn : (TT - 1);
                pf[u] = xq[base + (size_t)tc * 4];   // prefetch 16 ahead

                float gi = cur.x + h0 * Wi[0]  + h1 * Wi[1]  + h2 * Wi[2]  + h3 * Wi[3];
                float gf = cur.y + h0 * Wf4[0] + h1 * Wf4[1] + h2 * Wf4[2] + h3 * Wf4[3];
                float gg = cur.z + h0 * Wg[0]  + h1 * Wg[1]  + h2 * Wg[2]  + h3 * Wg[3];
                float go = cur.w + h0 * Wo[0]  + h1 * Wo[1]  + h2 * Wo[2]  + h3 * Wo[3];

                float si = fsigm(gi);
                float sf = fsigm(gf);
                float tg = ftanh(gg);
                float so = fsigm(go);

                c = sf * c + si * tg;
                float h = so * ftanh(c);

                h0 = quad_bcast<0>(h);
                h1 = quad_bcast<1>(h);
                h2 = quad_bcast<2>(h);
                h3 = quad_bcast<3>(h);
            }
        }
    }

    __syncthreads();

    if (tid < 64) {
        const int k  = tid & 3;
        const int bq = tid >> 2;
        const int b  = blockIdx.x * 16 + bq;

        float gib = bg[bq][k];
        float ggb = bg[bq][4 + k];
        float gob = bg[bq][8 + k];
        float hbk = fsigm(gob) * ftanh(fsigm(gib) * ftanh(ggb));
        float hb0 = quad_bcast<0>(hbk);
        float hb1 = quad_bcast<1>(hbk);
        float hb2 = quad_bcast<2>(hbk);
        float hb3 = quad_bcast<3>(hbk);

        float o0 = bout[0]
                 + h0  * Wout[0]  + h1  * Wout[1]  + h2  * Wout[2]  + h3  * Wout[3]
                 + hb0 * Wout[4]  + hb1 * Wout[5]  + hb2 * Wout[6]  + hb3 * Wout[7];
        float o1 = bout[1]
                 + h0  * Wout[8]  + h1  * Wout[9]  + h2  * Wout[10] + h3  * Wout[11]
                 + hb0 * Wout[12] + hb1 * Wout[13] + hb2 * Wout[14] + hb3 * Wout[15];

        if (k == 0) {
            out[b * 2 + 0] = o0;
            out[b * 2 + 1] = o1;
        }
    }
}

// ---------------------------------------------------------------------------
extern "C" void kernel_launch(void* const* d_in, const int* in_sizes, int n_in,
                              void* d_out, int out_size, void* d_ws, size_t ws_size,
                              hipStream_t stream)
{
    const float* x    = (const float*)d_in[0];
    const float* Wihf = (const float*)d_in[1];
    const float* Whhf = (const float*)d_in[2];
    const float* bihf = (const float*)d_in[3];
    const float* bhhf = (const float*)d_in[4];
    const float* Wihb = (const float*)d_in[5];
    const float* bihb = (const float*)d_in[7];
    const float* bhhb = (const float*)d_in[8];
    const float* Wout = (const float*)d_in[9];
    const float* bout = (const float*)d_in[10];

    float* xp = (float*)d_ws;   // 65536 rows x 16 floats = 4,194,304 B exactly

    // 65536 rows / 64 per block = 1024 blocks = exactly 4 resident per CU
    gemm_xp<<<1024, 256, 0, stream>>>(x, Wihf, bihf, bhhf, xp);
    frec<<<8, 256, 0, stream>>>(xp, x, Whhf, Wihb, bihb, bhhb, Wout, bout,
                                (float*)d_out);
}

// Round 6
// 435.381 us; speedup vs baseline: 1.3948x; 1.0348x over previous
//
#include <hip/hip_runtime.h>

#define IN 906
#define TT 512
#define NB 128

typedef float fv4 __attribute__((ext_vector_type(4)));

// 16B global load with only 4B alignment guaranteed (odd rows of x/W are
// 8B-aligned: 906 floats = 3624B per row). AMDGPU lowers align-4 <4 x float>
// loads to global_load_dwordx4 (dword alignment suffices on gfx9+).
__device__ __forceinline__ fv4 ldg4(const float* p) {
    fv4 v;
    __builtin_memcpy(&v, p, 16);
    return v;
}

// ---------------------------------------------------------------------------
__device__ __forceinline__ float fsigm(float x) {
    float e = __builtin_amdgcn_exp2f(-1.4426950408889634f * x);   // exp(-x)
    return __builtin_amdgcn_rcpf(1.f + e);
}
__device__ __forceinline__ float ftanh(float x) {
    float e = __builtin_amdgcn_exp2f(-2.8853900817779268f * x);   // exp(-2x)
    return 2.f * __builtin_amdgcn_rcpf(1.f + e) - 1.f;
}
template <int M>
__device__ __forceinline__ float quad_bcast(float v) {
    constexpr int ctrl = M | (M << 2) | (M << 4) | (M << 6);
    return __int_as_float(
        __builtin_amdgcn_mov_dpp(__float_as_int(v), ctrl, 0xf, 0xf, true));
}

// ---------------------------------------------------------------------------
// GEMM v7: xp = x @ W^T + b1 + b2, stored permuted xp[row][(j&3)*4 + (j>>2)].
//
// Diagnosis history: v3 ~98us and v6 ~117us scale with per-CU vector-memory
// REQUEST count (8B/lane-request staging: v3 4608 req/chunk-slot ~ 4055cyc
// observed; v6 5120 -> 117/98 = 5120/4608). Latency-depth (v6) and LDS-width
// (v3) changes were null => TA/request-rate bound.
//
// v7 halves the request count and keeps everything else off the critical
// path:
//   - 16B global loads (ldg4); staging wave-instr = 16 rows x 64B contiguous.
//   - LDS x-tile [64 rows][64 cols] row-major, XOR-swizzled slot = cg ^
//     ((row>>2)&7): ds_write_b128 staging, ds_read_b128 compute at <=2-way
//     (free). W-tile [16][64] swizzled cg ^ (j>>2): conflict-free.
//   - compute: thread = (kq 0..3, rg 0..15, og 0..3) = 4 rows x 4 outs x
//     16 cols/chunk, acc[4][4]; 64-col chunks => 15 barriers (was 29);
//     4 blocks/CU (LDS 40KB); one-time 4-way kq-merge via LDS (stride 17).
//   - plain launch_bounds (v5 spill lesson), ~100 VGPR.
// Floors: TA ~32us, LDS ~35-44us, HBM ~38us, VALU ~14us => gemm ~45-55us.
__global__ __launch_bounds__(256)
void gemm_xp(const float* __restrict__ x, const float* __restrict__ W,
             const float* __restrict__ b1, const float* __restrict__ b2,
             float* __restrict__ xp)
{
    __shared__ float sx[2][64][64];   // 32 KB  [buf][row][swizzled col]
    __shared__ float sw[2][16][64];   //  8 KB  [buf][j][swizzled col]
    const int tid = threadIdx.x;
    const size_t rowbase = (size_t)blockIdx.x * 64;

    // staging maps
    const int srow = tid >> 2;            // 0..63
    const int sseg = tid & 3;             // logical cg = q*4 + sseg
    const int sxsw = (srow >> 2) & 7;     // x store swizzle (= read's rg&7)
    const int wrow = tid >> 4;            // 0..15
    const int wseg = tid & 15;            // logical cg
    const int wssw = (wrow >> 2) & 3;     // w store swizzle (= read's og)

    // compute map
    const int kq = tid >> 6;              // 0..3 = wave id (k-quarter)
    const int rg = (tid >> 2) & 15;       // rows rg*4 .. rg*4+3
    const int og = tid & 3;               // outs og*4 .. og*4+3

    float acc[4][4] = {};
    fv4 xr[4];
    fv4 wr;

    const float* __restrict__ xrow = x + (rowbase + srow) * IN;
    const float* __restrict__ wrp  = W + wrow * IN;

    auto load_chunk = [&](int c) {
        const int k0 = c * 64;
        if (c < 14) {                      // cols k0..k0+63 all < 896+64
#pragma unroll
            for (int q = 0; q < 4; ++q)
                xr[q] = ldg4(xrow + k0 + (q * 4 + sseg) * 4);
            wr = ldg4(wrp + k0 + wseg * 4);
        } else {                           // tail: cols 896..905 valid
#pragma unroll
            for (int q = 0; q < 4; ++q) {
                const int col0 = k0 + (q * 4 + sseg) * 4;
#pragma unroll
                for (int e = 0; e < 4; ++e)
                    xr[q][e] = (col0 + e < IN) ? xrow[col0 + e] : 0.f;
            }
            const int colw0 = k0 + wseg * 4;
#pragma unroll
            for (int e = 0; e < 4; ++e)
                wr[e] = (colw0 + e < IN) ? wrp[colw0 + e] : 0.f;
        }
    };
    auto write_chunk = [&](int buf) {
#pragma unroll
        for (int q = 0; q < 4; ++q) {
            const int cg = q * 4 + sseg;
            *(fv4*)&sx[buf][srow][(cg ^ sxsw) * 4] = xr[q];
        }
        *(fv4*)&sw[buf][wrow][(wseg ^ wssw) * 4] = wr;
    };
    auto compute = [&](int buf) {
#pragma unroll
        for (int cg2 = 0; cg2 < 4; ++cg2) {
            const int cg = kq * 4 + cg2;
            const int xs = (cg ^ (rg & 7)) * 4;   // row>>2 == rg for all ri
            const int ws = (cg ^ og) * 4;         // j>>2  == og for all jj
            fv4 xv[4], wv[4];
#pragma unroll
            for (int ri = 0; ri < 4; ++ri)
                xv[ri] = *(const fv4*)&sx[buf][rg * 4 + ri][xs];
#pragma unroll
            for (int jj = 0; jj < 4; ++jj)
                wv[jj] = *(const fv4*)&sw[buf][og * 4 + jj][ws];
#pragma unroll
            for (int ri = 0; ri < 4; ++ri)
#pragma unroll
                for (int jj = 0; jj < 4; ++jj)
#pragma unroll
                    for (int e = 0; e < 4; ++e)
                        acc[ri][jj] = fmaf(xv[ri][e], wv[jj][e], acc[ri][jj]);
        }
    };

    load_chunk(0);
    write_chunk(0);
    __syncthreads();
    for (int c = 0; c < 15; ++c) {
        if (c < 14) load_chunk(c + 1);           // global loads in flight...
        compute(c & 1);                          // ...during compute
        if (c < 14) write_chunk((c + 1) & 1);
        __syncthreads();
    }

    // ---- one-time 4-way kq merge (red aliased onto sx[0]; compute done) ---
    // red[(kq-1)*64 + idx][17]: stride 17 => lane l hits bank l*17%32,
    // bijective over 32 banks for l 0..31; lanes 32..63 2-way (free).
    float* red = &sx[0][0][0];                   // 3*64*17*4 B = 13 KB < 16 KB
    const int idx = tid & 63;
    if (kq != 0) {
        float* rp = red + ((kq - 1) * 64 + idx) * 17;
#pragma unroll
        for (int ri = 0; ri < 4; ++ri)
#pragma unroll
            for (int jj = 0; jj < 4; ++jj)
                rp[ri * 4 + jj] = acc[ri][jj];
    }
    __syncthreads();
    if (kq == 0) {
#pragma unroll
        for (int ri = 0; ri < 4; ++ri) {
            const size_t row = rowbase + rg * 4 + ri;
#pragma unroll
            for (int jj = 0; jj < 4; ++jj) {
                float t = acc[ri][jj]
                        + red[(0 * 64 + idx) * 17 + ri * 4 + jj]
                        + red[(1 * 64 + idx) * 17 + ri * 4 + jj]
                        + red[(2 * 64 + idx) * 17 + ri * 4 + jj];
                const int j = og * 4 + jj;
                // permuted pos = (j&3)*4 + (j>>2) = jj*4 + og
                xp[row * 16 + jj * 4 + og] = t + b1[j] + b2[j];
            }
        }
    }
}

// ---------------------------------------------------------------------------
// Recurrence kernel: 8 blocks x 256 threads, 16 batches per block.
// wave 0: 512-step forward recurrence (quad per batch, DPP h-broadcast),
//         16-step-deep xp prefetch (covers ~900cyc cross-XCD/HBM latency;
//         depth 4 left steps memory-throttled at ~225cyc vs ~70cyc chain).
// waves 1-3: backward-direction GEMV (f-gate irrelevant, c0=0) -> LDS.
// epilogue (wave 0): backward cell + output projection.
__global__ __launch_bounds__(256)
void frec(const float* __restrict__ xp, const float* __restrict__ x,
          const float* __restrict__ Whh, const float* __restrict__ Wb,
          const float* __restrict__ bb1, const float* __restrict__ bb2,
          const float* __restrict__ Wout, const float* __restrict__ bout,
          float* __restrict__ out)
{
    __shared__ float bg[16][12];
    const int tid = threadIdx.x;

    float h0 = 0.f, h1 = 0.f, h2 = 0.f, h3 = 0.f;

    if (tid >= 64) {
        // ---- backward GEMV: 192 lanes = 16 batches x 12 gate rows ----
        const int gl = tid - 64;          // 0..191
        const int r  = gl >> 4;           // 0..11
        const int bq = gl & 15;
        const int b  = blockIdx.x * 16 + bq;
        const int gr = (r < 4) ? r : r + 4;   // rows: i 0-3, g 8-11, o 12-15
        const float2* __restrict__ xr  = (const float2*)(x + ((size_t)b * TT + (TT - 1)) * IN);
        const float2* __restrict__ wrp = (const float2*)(Wb + gr * IN);
        float s0 = 0.f, s1 = 0.f;
        int j = 0;
        for (; j + 8 <= 453; j += 8) {
#pragma unroll
            for (int u = 0; u < 8; ++u) {
                float2 a = xr[j + u];
                float2 w = wrp[j + u];
                s0 = fmaf(a.x, w.x, s0);
                s1 = fmaf(a.y, w.y, s1);
            }
        }
        for (; j < 453; ++j) {
            float2 a = xr[j];
            float2 w = wrp[j];
            s0 = fmaf(a.x, w.x, s0);
            s1 = fmaf(a.y, w.y, s1);
        }
        bg[bq][r] = s0 + s1 + bb1[gr] + bb2[gr];
    } else {
        // ---- forward recurrence ----
        const int k = tid & 3;
        const int b = blockIdx.x * 16 + (tid >> 2);

        float Wi[4], Wf4[4], Wg[4], Wo[4];
#pragma unroll
        for (int m = 0; m < 4; ++m) {
            Wi[m]  = Whh[(k)      * 4 + m];
            Wf4[m] = Whh[(4 + k)  * 4 + m];
            Wg[m]  = Whh[(8 + k)  * 4 + m];
            Wo[m]  = Whh[(12 + k) * 4 + m];
        }

        const float4* __restrict__ xq = (const float4*)xp;
        const size_t base = (size_t)b * TT * 4 + k;

        float4 pf[16];
#pragma unroll
        for (int i = 0; i < 16; ++i) pf[i] = xq[base + (size_t)i * 4];

        float c = 0.f;
        for (int t = 0; t < TT; t += 16) {
#pragma unroll
            for (int u = 0; u < 16; ++u) {
                float4 cur = pf[u];
                int tn = t + 16 + u;
                int tc = (tn < TT) ? tn : (TT - 1);
                pf[u] = xq[base + (size_t)tc * 4];   // prefetch 16 ahead

                float gi = cur.x + h0 * Wi[0]  + h1 * Wi[1]  + h2 * Wi[2]  + h3 * Wi[3];
                float gf = cur.y + h0 * Wf4[0] + h1 * Wf4[1] + h2 * Wf4[2] + h3 * Wf4[3];
                float gg = cur.z + h0 * Wg[0]  + h1 * Wg[1]  + h2 * Wg[2]  + h3 * Wg[3];
                float go = cur.w + h0 * Wo[0]  + h1 * Wo[1]  + h2 * Wo[2]  + h3 * Wo[3];

                float si = fsigm(gi);
                float sf = fsigm(gf);
                float tg = ftanh(gg);
                float so = fsigm(go);

                c = sf * c + si * tg;
                float h = so * ftanh(c);

                h0 = quad_bcast<0>(h);
                h1 = quad_bcast<1>(h);
                h2 = quad_bcast<2>(h);
                h3 = quad_bcast<3>(h);
            }
        }
    }

    __syncthreads();

    if (tid < 64) {
        const int k  = tid & 3;
        const int bq = tid >> 2;
        const int b  = blockIdx.x * 16 + bq;

        float gib = bg[bq][k];
        float ggb = bg[bq][4 + k];
        float gob = bg[bq][8 + k];
        float hbk = fsigm(gob) * ftanh(fsigm(gib) * ftanh(ggb));
        float hb0 = quad_bcast<0>(hbk);
        float hb1 = quad_bcast<1>(hbk);
        float hb2 = quad_bcast<2>(hbk);
        float hb3 = quad_bcast<3>(hbk);

        float o0 = bout[0]
                 + h0  * Wout[0]  + h1  * Wout[1]  + h2  * Wout[2]  + h3  * Wout[3]
                 + hb0 * Wout[4]  + hb1 * Wout[5]  + hb2 * Wout[6]  + hb3 * Wout[7];
        float o1 = bout[1]
                 + h0  * Wout[8]  + h1  * Wout[9]  + h2  * Wout[10] + h3  * Wout[11]
                 + hb0 * Wout[12] + hb1 * Wout[13] + hb2 * Wout[14] + hb3 * Wout[15];

        if (k == 0) {
            out[b * 2 + 0] = o0;
            out[b * 2 + 1] = o1;
        }
    }
}

// ---------------------------------------------------------------------------
extern "C" void kernel_launch(void* const* d_in, const int* in_sizes, int n_in,
                              void* d_out, int out_size, void* d_ws, size_t ws_size,
                              hipStream_t stream)
{
    const float* x    = (const float*)d_in[0];
    const float* Wihf = (const float*)d_in[1];
    const float* Whhf = (const float*)d_in[2];
    const float* bihf = (const float*)d_in[3];
    const float* bhhf = (const float*)d_in[4];
    const float* Wihb = (const float*)d_in[5];
    const float* bihb = (const float*)d_in[7];
    const float* bhhb = (const float*)d_in[8];
    const float* Wout = (const float*)d_in[9];
    const float* bout = (const float*)d_in[10];

    float* xp = (float*)d_ws;   // 65536 rows x 16 floats = 4,194,304 B exactly

    // 65536 rows / 64 per block = 1024 blocks (4 resident per CU at 40KB LDS)
    gemm_xp<<<1024, 256, 0, stream>>>(x, Wihf, bihf, bhhf, xp);
    frec<<<8, 256, 0, stream>>>(xp, x, Whhf, Wihb, bihb, bhhb, Wout, bout,
                                (float*)d_out);
}